// Round 2
// baseline (890.107 us; speedup 1.0000x reference)
//
#include <hip/hip_runtime.h>
#include <hip/hip_bf16.h>

typedef unsigned short u16;
typedef __attribute__((ext_vector_type(8))) short shortx8;
typedef __attribute__((ext_vector_type(4))) float floatx4;

// ---------- helpers ----------
__device__ __forceinline__ float bf2f(u16 u) {
    union { unsigned int ui; float f; } x; x.ui = ((unsigned int)u) << 16; return x.f;
}
__device__ __forceinline__ u16 f2b(float f) {
    union { float f; unsigned int u; } x; x.f = f;
    unsigned int r = (x.u + 0x7fffu + ((x.u >> 16) & 1u)) >> 16;   // RNE
    return (u16)r;
}
__device__ __forceinline__ void glds16(const void* g, void* l) {
    __builtin_amdgcn_global_load_lds((const __attribute__((address_space(1))) void*)g,
                                     (__attribute__((address_space(3))) void*)l, 16, 0, 0);
}

// ---------- fp32 -> bf16 elementwise (encodings) ----------
__global__ __launch_bounds__(256) void cvt_bf16_kernel(const float* __restrict__ src,
                                                       u16* __restrict__ dst, int n) {
    int i = (blockIdx.x * 256 + threadIdx.x) * 4;
    if (i + 3 < n) {
        float4 v = *(const float4*)&src[i];
        ushort4 o; o.x = f2b(v.x); o.y = f2b(v.y); o.z = f2b(v.z); o.w = f2b(v.w);
        *(ushort4*)&dst[i] = o;
    }
}

// ---------- build Bsmall' [1024][512] bf16 via coalesced LDS transpose ----------
// sources: mu/sg/b1/b2 each [512 k][256 c] fp32 -> Bs[src*256 + c][k] bf16
__global__ __launch_bounds__(256) void build_bsmall_t(const float* __restrict__ mu,
                                                      const float* __restrict__ sg,
                                                      const float* __restrict__ b1,
                                                      const float* __restrict__ b2,
                                                      u16* __restrict__ Bs) {
    __shared__ float t[32][33];
    const float* src;
    int z = blockIdx.z;
    if (z == 0) src = mu; else if (z == 1) src = sg; else if (z == 2) src = b1; else src = b2;
    int k0 = blockIdx.x * 32, c0 = blockIdx.y * 32;
    int r = threadIdx.x >> 3, c4 = (threadIdx.x & 7) * 4;
    float4 v = *(const float4*)&src[(size_t)(k0 + r) * 256 + c0 + c4];
    t[r][c4] = v.x; t[r][c4 + 1] = v.y; t[r][c4 + 2] = v.z; t[r][c4 + 3] = v.w;
    __syncthreads();
    ushort4 o;
    o.x = f2b(t[c4 + 0][r]); o.y = f2b(t[c4 + 1][r]);
    o.z = f2b(t[c4 + 2][r]); o.w = f2b(t[c4 + 3][r]);
    *(ushort4*)&Bs[(size_t)(z * 256 + c0 + r) * 512 + k0 + c4] = o;
}

// ---------- fc_w fp32 [512][65536] -> bf16 transposed [65536][512] ----------
__global__ __launch_bounds__(256) void cvt_transpose(const float* __restrict__ W,
                                                     u16* __restrict__ Bt) {
    __shared__ float t[32][33];
    int n0 = blockIdx.x * 32, k0 = blockIdx.y * 32;
    int r  = threadIdx.x >> 3, c4 = (threadIdx.x & 7) * 4;
    float4 v = *(const float4*)&W[(size_t)(k0 + r) * 65536 + n0 + c4];
    t[r][c4] = v.x; t[r][c4 + 1] = v.y; t[r][c4 + 2] = v.z; t[r][c4 + 3] = v.w;
    __syncthreads();
    ushort4 o;
    o.x = f2b(t[c4 + 0][r]); o.y = f2b(t[c4 + 1][r]);
    o.z = f2b(t[c4 + 2][r]); o.w = f2b(t[c4 + 3][r]);
    *(ushort4*)&Bt[(size_t)(n0 + r) * 512 + k0 + c4] = o;
}

// ---------- slots = mu + exp(0.5*sig)*eps ----------
__global__ __launch_bounds__(256) void slots_kernel(const float* __restrict__ P,
                                                    const float* __restrict__ eps,
                                                    float* __restrict__ slots) {
    int t = blockIdx.x, d = threadIdx.x;
    float mu = P[(size_t)t * 1024 + d];
    float sg = expf(0.5f * P[(size_t)t * 1024 + 256 + d]);
    int b = t >> 6, n = t & 63;
    #pragma unroll
    for (int m = 0; m < 2; m++) {
        float e = eps[(size_t)(((b * 2 + m) * 64) + n) * 256 + d];
        slots[(size_t)t * 512 + m * 256 + d] = mu + sg * e;
    }
}

// ---------- MFMA GEMM: C[M][N] = A[M][K] * B'[N][K]^T  (bf16 in, fp32 acc) ----------
// BK=64, XOR-swizzled 16B k-chunks (chunk_phys = chunk_log ^ (row&7)) to kill
// the 8-way ds_read_b128 bank conflicts while keeping glds wave-uniform dests.
template<int OUT_BF16>
__global__ __launch_bounds__(256, 2) void gemm_bt(const u16* __restrict__ A,
                                                  const u16* __restrict__ B,
                                                  void* __restrict__ Cv,
                                                  int N, int K) {
    __shared__ __align__(16) u16 As[128 * 64];
    __shared__ __align__(16) u16 Bs[128 * 64];
    int tid = threadIdx.x;
    int wave = tid >> 6, lane = tid & 63;
    int m0 = blockIdx.x * 128, n0 = blockIdx.y * 128;
    int wm = wave >> 1, wn = wave & 1;

    floatx4 acc[4][4];
    #pragma unroll
    for (int r = 0; r < 4; r++)
        #pragma unroll
        for (int c = 0; c < 4; c++)
            #pragma unroll
            for (int q = 0; q < 4; q++) acc[r][c][q] = 0.f;

    // loader precompute: chunk j of this wave covers rows r0..r0+7 (128B each)
    int lrsub = lane >> 3;                 // 0..7 within chunk
    int kcl   = lane & 7;                  // logical 16B chunk within row
    const u16* gA[4]; const u16* gB[4]; u16* lA[4]; u16* lB[4];
    #pragma unroll
    for (int j = 0; j < 4; j++) {
        int r0 = (wave * 4 + j) * 8;
        int row = r0 + lrsub;
        int kof = (kcl ^ (row & 7)) * 8;   // swizzled element offset in row
        gA[j] = A + (size_t)(m0 + row) * K + kof;
        gB[j] = B + (size_t)(n0 + row) * K + kof;
        lA[j] = As + r0 * 64;
        lB[j] = Bs + r0 * 64;
    }

    // fragment read precompute
    int arb = wm * 64 + (lane & 15);       // A row base (r*16 added later; 16%8==0)
    int brb = wn * 64 + (lane & 15);
    int axr = arb & 7, bxr = brb & 7;
    int cl0 = lane >> 4;                   // logical chunk low part

    for (int k0 = 0; k0 < K; k0 += 64) {
        #pragma unroll
        for (int j = 0; j < 4; j++) glds16(gA[j] + k0, lA[j]);
        #pragma unroll
        for (int j = 0; j < 4; j++) glds16(gB[j] + k0, lB[j]);
        __syncthreads();
        #pragma unroll
        for (int s = 0; s < 2; s++) {
            shortx8 af[4], bf[4];
            int ac = ((s * 4 + cl0) ^ axr) * 8;
            int bc = ((s * 4 + cl0) ^ bxr) * 8;
            #pragma unroll
            for (int r = 0; r < 4; r++) af[r] = *(const shortx8*)(As + (arb + r * 16) * 64 + ac);
            #pragma unroll
            for (int c = 0; c < 4; c++) bf[c] = *(const shortx8*)(Bs + (brb + c * 16) * 64 + bc);
            #pragma unroll
            for (int r = 0; r < 4; r++)
                #pragma unroll
                for (int c = 0; c < 4; c++)
                    acc[r][c] = __builtin_amdgcn_mfma_f32_16x16x32_bf16(af[r], bf[c], acc[r][c], 0, 0, 0);
        }
        __syncthreads();
    }

    int crow0 = m0 + wm * 64 + (lane >> 4) * 4;
    int ccol  = n0 + wn * 64 + (lane & 15);
    if (OUT_BF16) {
        u16* C = (u16*)Cv;
        #pragma unroll
        for (int r = 0; r < 4; r++)
            #pragma unroll
            for (int c = 0; c < 4; c++)
                #pragma unroll
                for (int q = 0; q < 4; q++)
                    __builtin_nontemporal_store(f2b(acc[r][c][q]),
                        &C[(size_t)(crow0 + r * 16 + q) * N + ccol + c * 16]);
    } else {
        float* C = (float*)Cv;
        #pragma unroll
        for (int r = 0; r < 4; r++)
            #pragma unroll
            for (int c = 0; c < 4; c++)
                #pragma unroll
                for (int q = 0; q < 4; q++)
                    C[(size_t)(crow0 + r * 16 + q) * N + ccol + c * 16] = acc[r][c][q];
    }
}

// ---------- apply: y[t][m][h] = relu(sum_g s[t][m][g]*W[t][g][h] + bias[t][h]) ----------
__global__ __launch_bounds__(256) void apply_mlp(const u16* __restrict__ Wc,   // [NT][256][256] bf16
                                                 const float* __restrict__ P,  // [2048][1024]
                                                 const float* __restrict__ sin,// [2048][2][256]
                                                 float* __restrict__ yout,
                                                 int t0, int bias_col, int final_layout) {
    __shared__ float s[2][256];
    __shared__ float part[8][2][256];
    int tid = threadIdx.x;
    int tloc = blockIdx.x;
    int t = t0 + tloc;
    s[0][tid] = sin[(size_t)t * 512 + tid];
    s[1][tid] = sin[(size_t)t * 512 + 256 + tid];
    __syncthreads();

    int j = tid & 31, gg = tid >> 5;
    int jh = j * 8;
    float f0[8], f1[8];
    #pragma unroll
    for (int i = 0; i < 8; i++) { f0[i] = 0.f; f1[i] = 0.f; }
    const u16* wp = Wc + (size_t)tloc * 65536 + jh;
    for (int g = gg; g < 256; g += 8) {
        shortx8 wv = *(const shortx8*)(wp + (size_t)g * 256);
        float s0 = s[0][g], s1 = s[1][g];
        #pragma unroll
        for (int i = 0; i < 8; i++) {
            float w = bf2f((u16)wv[i]);
            f0[i] += s0 * w;
            f1[i] += s1 * w;
        }
    }
    float4* p0 = (float4*)&part[gg][0][jh];
    float4* p1 = (float4*)&part[gg][1][jh];
    float4 a0; a0.x = f0[0]; a0.y = f0[1]; a0.z = f0[2]; a0.w = f0[3];
    float4 a1; a1.x = f0[4]; a1.y = f0[5]; a1.z = f0[6]; a1.w = f0[7];
    float4 b0; b0.x = f1[0]; b0.y = f1[1]; b0.z = f1[2]; b0.w = f1[3];
    float4 b1; b1.x = f1[4]; b1.y = f1[5]; b1.z = f1[6]; b1.w = f1[7];
    p0[0] = a0; p0[1] = a1; p1[0] = b0; p1[1] = b1;
    __syncthreads();

    float bias = P[(size_t)t * 1024 + bias_col + tid];
    float y0 = bias, y1 = bias;
    #pragma unroll
    for (int p = 0; p < 8; p++) { y0 += part[p][0][tid]; y1 += part[p][1][tid]; }
    y0 = fmaxf(y0, 0.f); y1 = fmaxf(y1, 0.f);
    if (final_layout) {
        int b = t >> 6, n = t & 63;
        yout[(size_t)((b * 2 + 0) * 64 + n) * 256 + tid] = y0;
        yout[(size_t)((b * 2 + 1) * 64 + n) * 256 + tid] = y1;
    } else {
        yout[(size_t)t * 512 + tid] = y0;
        yout[(size_t)t * 512 + 256 + tid] = y1;
    }
}

// ---------- host ----------
extern "C" void kernel_launch(void* const* d_in, const int* in_sizes, int n_in,
                              void* d_out, int out_size, void* d_ws, size_t ws_size,
                              hipStream_t stream) {
    const float* enc = (const float*)d_in[0];
    const float* mu  = (const float*)d_in[1];
    const float* sg  = (const float*)d_in[2];
    const float* f1w = (const float*)d_in[3];
    const float* f1b = (const float*)d_in[4];
    const float* f2w = (const float*)d_in[5];
    const float* f2b = (const float*)d_in[6];
    const float* eps = (const float*)d_in[7];
    float* out = (float*)d_out;

    size_t off = 0;
    auto alloc = [&](size_t b) -> char* {
        char* p = (char*)d_ws + off; off += (b + 255) & ~(size_t)255; return p;
    };
    u16*   Eb    = (u16*)  alloc((size_t)2048 * 512 * 2);
    float* P     = (float*)alloc((size_t)2048 * 1024 * 4);
    float* slots = (float*)alloc((size_t)2048 * 512 * 4);
    float* h1    = (float*)alloc((size_t)2048 * 512 * 4);
    u16*   Bsm   = (u16*)  alloc((size_t)1024 * 512 * 2);
    u16*   Bt    = (u16*)  alloc((size_t)65536 * 512 * 2);
    size_t fixed = off;
    int NT = 2048;
    while (NT > 128 && fixed + (size_t)NT * 65536 * 2 > ws_size) NT >>= 1;
    u16* Wc = (u16*)alloc((size_t)NT * 65536 * 2);

    cvt_bf16_kernel<<<1024, 256, 0, stream>>>(enc, Eb, 2048 * 512);
    build_bsmall_t<<<dim3(16, 8, 4), 256, 0, stream>>>(mu, sg, f1b, f2b, Bsm);
    gemm_bt<0><<<dim3(16, 8), 256, 0, stream>>>(Eb, Bsm, P, 1024, 512);
    slots_kernel<<<2048, 256, 0, stream>>>(P, eps, slots);

    for (int L = 0; L < 2; L++) {
        const float* fw = L ? f2w : f1w;
        cvt_transpose<<<dim3(2048, 16), 256, 0, stream>>>(fw, Bt);
        const float* sin_p = L ? h1 : slots;
        float* yo = L ? out : h1;
        for (int t0 = 0; t0 < 2048; t0 += NT) {
            gemm_bt<1><<<dim3(NT / 128, 512), 256, 0, stream>>>(Eb + (size_t)t0 * 512, Bt, Wc, 65536, 512);
            apply_mlp<<<NT, 256, 0, stream>>>(Wc, P, sin_p, yo, t0, 512 + L * 256, L);
        }
    }
}

// Round 3
// 847.498 us; speedup vs baseline: 1.0503x; 1.0503x over previous
//
#include <hip/hip_runtime.h>
#include <hip/hip_bf16.h>

typedef unsigned short u16;
typedef __attribute__((ext_vector_type(8))) short shortx8;
typedef __attribute__((ext_vector_type(4))) float floatx4;

// ---------- helpers ----------
__device__ __forceinline__ float bf2f(u16 u) {
    union { unsigned int ui; float f; } x; x.ui = ((unsigned int)u) << 16; return x.f;
}
__device__ __forceinline__ u16 f2b(float f) {
    union { float f; unsigned int u; } x; x.f = f;
    unsigned int r = (x.u + 0x7fffu + ((x.u >> 16) & 1u)) >> 16;   // RNE
    return (u16)r;
}
__device__ __forceinline__ void glds16(const void* g, void* l) {
    __builtin_amdgcn_global_load_lds((const __attribute__((address_space(1))) void*)g,
                                     (__attribute__((address_space(3))) void*)l, 16, 0, 0);
}

// ---------- fp32 -> bf16 elementwise (encodings) ----------
__global__ __launch_bounds__(256) void cvt_bf16_kernel(const float* __restrict__ src,
                                                       u16* __restrict__ dst, int n) {
    int i = (blockIdx.x * 256 + threadIdx.x) * 4;
    if (i + 3 < n) {
        float4 v = *(const float4*)&src[i];
        ushort4 o; o.x = f2b(v.x); o.y = f2b(v.y); o.z = f2b(v.z); o.w = f2b(v.w);
        *(ushort4*)&dst[i] = o;
    }
}

// ---------- build Bsmall' [1024][512] bf16 via coalesced LDS transpose ----------
__global__ __launch_bounds__(256) void build_bsmall_t(const float* __restrict__ mu,
                                                      const float* __restrict__ sg,
                                                      const float* __restrict__ b1,
                                                      const float* __restrict__ b2,
                                                      u16* __restrict__ Bs) {
    __shared__ float t[32][33];
    const float* src;
    int z = blockIdx.z;
    if (z == 0) src = mu; else if (z == 1) src = sg; else if (z == 2) src = b1; else src = b2;
    int k0 = blockIdx.x * 32, c0 = blockIdx.y * 32;
    int r = threadIdx.x >> 3, c4 = (threadIdx.x & 7) * 4;
    float4 v = *(const float4*)&src[(size_t)(k0 + r) * 256 + c0 + c4];
    t[r][c4] = v.x; t[r][c4 + 1] = v.y; t[r][c4 + 2] = v.z; t[r][c4 + 3] = v.w;
    __syncthreads();
    ushort4 o;
    o.x = f2b(t[c4 + 0][r]); o.y = f2b(t[c4 + 1][r]);
    o.z = f2b(t[c4 + 2][r]); o.w = f2b(t[c4 + 3][r]);
    *(ushort4*)&Bs[(size_t)(z * 256 + c0 + r) * 512 + k0 + c4] = o;
}

// ---------- fc_w fp32 [512][65536] -> bf16 transposed [65536][512] ----------
__global__ __launch_bounds__(256) void cvt_transpose(const float* __restrict__ W,
                                                     u16* __restrict__ Bt) {
    __shared__ float t[32][33];
    int n0 = blockIdx.x * 32, k0 = blockIdx.y * 32;
    int r  = threadIdx.x >> 3, c4 = (threadIdx.x & 7) * 4;
    float4 v = *(const float4*)&W[(size_t)(k0 + r) * 65536 + n0 + c4];
    t[r][c4] = v.x; t[r][c4 + 1] = v.y; t[r][c4 + 2] = v.z; t[r][c4 + 3] = v.w;
    __syncthreads();
    ushort4 o;
    o.x = f2b(t[c4 + 0][r]); o.y = f2b(t[c4 + 1][r]);
    o.z = f2b(t[c4 + 2][r]); o.w = f2b(t[c4 + 3][r]);
    *(ushort4*)&Bt[(size_t)(n0 + r) * 512 + k0 + c4] = o;
}

// ---------- slots = mu + exp(0.5*sig)*eps ----------
__global__ __launch_bounds__(256) void slots_kernel(const float* __restrict__ P,
                                                    const float* __restrict__ eps,
                                                    float* __restrict__ slots) {
    int t = blockIdx.x, d = threadIdx.x;
    float mu = P[(size_t)t * 1024 + d];
    float sg = expf(0.5f * P[(size_t)t * 1024 + 256 + d]);
    int b = t >> 6, n = t & 63;
    #pragma unroll
    for (int m = 0; m < 2; m++) {
        float e = eps[(size_t)(((b * 2 + m) * 64) + n) * 256 + d];
        slots[(size_t)t * 512 + m * 256 + d] = mu + sg * e;
    }
}

// ---------- MFMA GEMM: C = A[M][K] * B'[N][K]^T, bf16 in / fp32 acc ----------
// 1D grid with XCD-aware decode: xcd = id&7 keeps all bx (m-blocks) of one by
// (B-tile) on the same XCD L2.  BK=64, XOR-swizzled LDS (0 conflicts).
// OUT_BF16=1: wave-tiled epilogue -> Wc layout:
//   elem = tile*16384 + wave*4096 + r*1024 + c*256 + lane16*16 + lq*4 + q
//   (tile = by*nbx + bx; row-in-tile = wm*64 + r*16 + lq*4 + q; col = wn*64+c*16+lane16)
template<int OUT_BF16>
__global__ __launch_bounds__(256, 2) void gemm_bt(const u16* __restrict__ A,
                                                  const u16* __restrict__ B,
                                                  void* __restrict__ Cv,
                                                  int N, int K,
                                                  int nbx_l2, int bypx_l2) {
    __shared__ __align__(16) u16 As[128 * 64];
    __shared__ __align__(16) u16 Bs[128 * 64];
    int tid = threadIdx.x;
    int wave = tid >> 6, lane = tid & 63;

    int id = blockIdx.x;
    int xcd = id & 7, sq = id >> 3;
    int by = (xcd << bypx_l2) + (sq >> nbx_l2);
    int bx = sq & ((1 << nbx_l2) - 1);
    int m0 = bx * 128, n0 = by * 128;
    int wm = wave >> 1, wn = wave & 1;

    floatx4 acc[4][4];
    #pragma unroll
    for (int r = 0; r < 4; r++)
        #pragma unroll
        for (int c = 0; c < 4; c++)
            #pragma unroll
            for (int q = 0; q < 4; q++) acc[r][c][q] = 0.f;

    int lrsub = lane >> 3;
    int kcl   = lane & 7;
    const u16* gA[4]; const u16* gB[4]; u16* lA[4]; u16* lB[4];
    #pragma unroll
    for (int j = 0; j < 4; j++) {
        int r0 = (wave * 4 + j) * 8;
        int row = r0 + lrsub;
        int kof = (kcl ^ (row & 7)) * 8;
        gA[j] = A + (size_t)(m0 + row) * K + kof;
        gB[j] = B + (size_t)(n0 + row) * K + kof;
        lA[j] = As + r0 * 64;
        lB[j] = Bs + r0 * 64;
    }

    int arb = wm * 64 + (lane & 15);
    int brb = wn * 64 + (lane & 15);
    int axr = arb & 7, bxr = brb & 7;
    int cl0 = lane >> 4;

    for (int k0 = 0; k0 < K; k0 += 64) {
        #pragma unroll
        for (int j = 0; j < 4; j++) glds16(gA[j] + k0, lA[j]);
        #pragma unroll
        for (int j = 0; j < 4; j++) glds16(gB[j] + k0, lB[j]);
        __syncthreads();
        #pragma unroll
        for (int s = 0; s < 2; s++) {
            shortx8 af[4], bf[4];
            int ac = ((s * 4 + cl0) ^ axr) * 8;
            int bc = ((s * 4 + cl0) ^ bxr) * 8;
            #pragma unroll
            for (int r = 0; r < 4; r++) af[r] = *(const shortx8*)(As + (arb + r * 16) * 64 + ac);
            #pragma unroll
            for (int c = 0; c < 4; c++) bf[c] = *(const shortx8*)(Bs + (brb + c * 16) * 64 + bc);
            #pragma unroll
            for (int r = 0; r < 4; r++)
                #pragma unroll
                for (int c = 0; c < 4; c++)
                    acc[r][c] = __builtin_amdgcn_mfma_f32_16x16x32_bf16(af[r], bf[c], acc[r][c], 0, 0, 0);
        }
        __syncthreads();
    }

    if (OUT_BF16) {
        u16* C = (u16*)Cv;
        size_t base = ((size_t)((by << nbx_l2) + bx) << 14) + ((size_t)wave << 12)
                    + (lane & 15) * 16 + (lane >> 4) * 4;
        #pragma unroll
        for (int r = 0; r < 4; r++)
            #pragma unroll
            for (int c = 0; c < 4; c++) {
                ushort4 o;
                o.x = f2b(acc[r][c][0]); o.y = f2b(acc[r][c][1]);
                o.z = f2b(acc[r][c][2]); o.w = f2b(acc[r][c][3]);
                *(ushort4*)(C + base + r * 1024 + c * 256) = o;
            }
    } else {
        float* C = (float*)Cv;
        int crow0 = m0 + wm * 64 + (lane >> 4) * 4;
        int ccol  = n0 + wn * 64 + (lane & 15);
        #pragma unroll
        for (int r = 0; r < 4; r++)
            #pragma unroll
            for (int c = 0; c < 4; c++)
                #pragma unroll
                for (int q = 0; q < 4; q++)
                    C[(size_t)(crow0 + r * 16 + q) * N + ccol + c * 16] = acc[r][c][q];
    }
}

// ---------- apply v2: reads wave-tiled Wc ----------
// block = (16-token group tgi, h-32-slice hq); threads: gg = tid>>5 (8 g-streams),
// hl = tid&31 (h lane). Each thread accumulates y[16t][2m] for its h over g≡gg(8).
__global__ __launch_bounds__(256, 2) void apply_mlp2(const u16* __restrict__ Wc,
                                                     const float* __restrict__ P,
                                                     const float* __restrict__ sin_p,
                                                     float* __restrict__ yout,
                                                     int t0, int nbx_l2,
                                                     int bias_col, int final_layout) {
    __shared__ float sl[8192];            // [g][m][ti] : 32 KB
    __shared__ float4 red[8][256];        // [j>>2][gg*32+hl] : 32 KB
    int tid = threadIdx.x;
    int tloc = blockIdx.x * 16;           // token base within chunk
    int tg0 = t0 + tloc;                  // global token base
    int hq = blockIdx.y;

    for (int i = tid; i < 8192; i += 256) {
        int g = i >> 5, m = (i >> 4) & 1, ti = i & 15;
        sl[i] = sin_p[(size_t)(tg0 + ti) * 512 + m * 256 + g];
    }
    __syncthreads();

    int gg = tid >> 5, hl = tid & 31;
    int h = hq * 32 + hl;
    int bx = tloc >> 7, wm = (tloc >> 6) & 1, r = (tloc >> 4) & 3;

    float acc[32];
    #pragma unroll
    for (int j = 0; j < 32; j++) acc[j] = 0.f;

    for (int it = 0; it < 32; it++) {
        int g = gg + it * 8;
        int n = g * 256 + h;
        int by = n >> 7, wn = (n >> 6) & 1, c = (n >> 4) & 3, l16 = n & 15;
        size_t elem = ((size_t)((by << nbx_l2) + bx) << 14)
                    + ((size_t)(wm * 2 + wn) << 12) + (r << 10) + (c << 8) + (l16 << 4);
        shortx8 w0 = *(const shortx8*)(Wc + elem);
        shortx8 w1 = *(const shortx8*)(Wc + elem + 8);
        const float4* sp = (const float4*)&sl[g << 5];
        float4 sv[8];
        #pragma unroll
        for (int j = 0; j < 8; j++) sv[j] = sp[j];
        float wf[16];
        #pragma unroll
        for (int i = 0; i < 8; i++) wf[i] = bf2f((u16)w0[i]);
        #pragma unroll
        for (int i = 0; i < 8; i++) wf[8 + i] = bf2f((u16)w1[i]);
        const float* sf = (const float*)sv;
        #pragma unroll
        for (int j = 0; j < 32; j++)
            acc[j] += sf[j] * wf[j & 15];
    }

    #pragma unroll
    for (int jq = 0; jq < 8; jq++) {
        float4 v; v.x = acc[jq * 4]; v.y = acc[jq * 4 + 1];
        v.z = acc[jq * 4 + 2]; v.w = acc[jq * 4 + 3];
        red[jq][gg * 32 + hl] = v;
    }
    __syncthreads();

    #pragma unroll
    for (int k = 0; k < 4; k++) {
        int idx = k * 256 + tid;          // 1024 outputs: [j2 0..31][hl2 0..31]
        int hl2 = idx & 31, j2 = (idx >> 5) & 31;
        int m = j2 >> 4, ti = j2 & 15;
        float y = 0.f;
        #pragma unroll
        for (int g2 = 0; g2 < 8; g2++) {
            float4 v = red[j2 >> 2][g2 * 32 + hl2];
            y += ((const float*)&v)[j2 & 3];
        }
        int t = tg0 + ti, h2 = hq * 32 + hl2;
        y += P[(size_t)t * 1024 + bias_col + h2];
        y = fmaxf(y, 0.f);
        if (final_layout)
            yout[(size_t)(((t >> 6) * 2 + m) * 64 + (t & 63)) * 256 + h2] = y;
        else
            yout[(size_t)t * 512 + m * 256 + h2] = y;
    }
}

// ---------- host ----------
extern "C" void kernel_launch(void* const* d_in, const int* in_sizes, int n_in,
                              void* d_out, int out_size, void* d_ws, size_t ws_size,
                              hipStream_t stream) {
    const float* enc = (const float*)d_in[0];
    const float* mu  = (const float*)d_in[1];
    const float* sg  = (const float*)d_in[2];
    const float* f1w = (const float*)d_in[3];
    const float* f1b = (const float*)d_in[4];
    const float* f2w = (const float*)d_in[5];
    const float* f2b = (const float*)d_in[6];
    const float* eps = (const float*)d_in[7];
    float* out = (float*)d_out;

    size_t off = 0;
    auto alloc = [&](size_t b) -> char* {
        char* p = (char*)d_ws + off; off += (b + 255) & ~(size_t)255; return p;
    };
    u16*   Eb    = (u16*)  alloc((size_t)2048 * 512 * 2);
    float* P     = (float*)alloc((size_t)2048 * 1024 * 4);
    float* slots = (float*)alloc((size_t)2048 * 512 * 4);
    float* h1    = (float*)alloc((size_t)2048 * 512 * 4);
    u16*   Bsm   = (u16*)  alloc((size_t)1024 * 512 * 2);
    u16*   Bt    = (u16*)  alloc((size_t)65536 * 512 * 2);
    size_t fixed = off;
    // NT=512 keeps the Wc chunk (67 MB) LLC-resident between gemm and apply.
    int NT = 512;
    while (NT > 128 && fixed + (size_t)NT * 65536 * 2 > ws_size) NT >>= 1;
    u16* Wc = (u16*)alloc((size_t)NT * 65536 * 2);
    int nbx_l2 = (NT == 512) ? 2 : (NT == 256 ? 1 : 0);

    cvt_bf16_kernel<<<1024, 256, 0, stream>>>(enc, Eb, 2048 * 512);
    build_bsmall_t<<<dim3(16, 8, 4), 256, 0, stream>>>(mu, sg, f1b, f2b, Bsm);
    // P gemm: M=2048,N=1024 -> nbx=16 (l2=4), by-per-xcd=1 (l2=0), 128 blocks
    gemm_bt<0><<<128, 256, 0, stream>>>(Eb, Bsm, P, 1024, 512, 4, 0);
    slots_kernel<<<2048, 256, 0, stream>>>(P, eps, slots);

    for (int L = 0; L < 2; L++) {
        const float* fw = L ? f2w : f1w;
        cvt_transpose<<<dim3(2048, 16), 256, 0, stream>>>(fw, Bt);
        const float* sin_p = L ? h1 : slots;
        float* yo = L ? out : h1;
        for (int t0 = 0; t0 < 2048; t0 += NT) {
            gemm_bt<1><<<(NT / 128) * 512, 256, 0, stream>>>(
                Eb + (size_t)t0 * 512, Bt, Wc, 65536, 512, nbx_l2, 6);
            apply_mlp2<<<dim3(NT / 16, 8), 256, 0, stream>>>(
                Wc, P, sin_p, yo, t0, nbx_l2, 512 + L * 256, L);
        }
    }
}

// Round 4
// 759.387 us; speedup vs baseline: 1.1721x; 1.1160x over previous
//
#include <hip/hip_runtime.h>
#include <hip/hip_bf16.h>

typedef unsigned short u16;
typedef __attribute__((ext_vector_type(8))) short shortx8;
typedef __attribute__((ext_vector_type(4))) float floatx4;

// ---------- helpers ----------
__device__ __forceinline__ float bf2f(u16 u) {
    union { unsigned int ui; float f; } x; x.ui = ((unsigned int)u) << 16; return x.f;
}
__device__ __forceinline__ u16 f2b(float f) {
    union { float f; unsigned int u; } x; x.f = f;
    unsigned int r = (x.u + 0x7fffu + ((x.u >> 16) & 1u)) >> 16;   // RNE
    return (u16)r;
}
__device__ __forceinline__ void glds16(const void* g, void* l) {
    __builtin_amdgcn_global_load_lds((const __attribute__((address_space(1))) void*)g,
                                     (__attribute__((address_space(3))) void*)l, 16, 0, 0);
}

// ---------- fp32 -> bf16 elementwise (encodings) ----------
__global__ __launch_bounds__(256) void cvt_bf16_kernel(const float* __restrict__ src,
                                                       u16* __restrict__ dst, int n) {
    int i = (blockIdx.x * 256 + threadIdx.x) * 4;
    if (i + 3 < n) {
        float4 v = *(const float4*)&src[i];
        ushort4 o; o.x = f2b(v.x); o.y = f2b(v.y); o.z = f2b(v.z); o.w = f2b(v.w);
        *(ushort4*)&dst[i] = o;
    }
}

// ---------- build Bsmall' [1024][512] bf16 via coalesced LDS transpose ----------
__global__ __launch_bounds__(256) void build_bsmall_t(const float* __restrict__ mu,
                                                      const float* __restrict__ sg,
                                                      const float* __restrict__ b1,
                                                      const float* __restrict__ b2,
                                                      u16* __restrict__ Bs) {
    __shared__ float t[32][33];
    const float* src;
    int z = blockIdx.z;
    if (z == 0) src = mu; else if (z == 1) src = sg; else if (z == 2) src = b1; else src = b2;
    int k0 = blockIdx.x * 32, c0 = blockIdx.y * 32;
    int r = threadIdx.x >> 3, c4 = (threadIdx.x & 7) * 4;
    float4 v = *(const float4*)&src[(size_t)(k0 + r) * 256 + c0 + c4];
    t[r][c4] = v.x; t[r][c4 + 1] = v.y; t[r][c4 + 2] = v.z; t[r][c4 + 3] = v.w;
    __syncthreads();
    ushort4 o;
    o.x = f2b(t[c4 + 0][r]); o.y = f2b(t[c4 + 1][r]);
    o.z = f2b(t[c4 + 2][r]); o.w = f2b(t[c4 + 3][r]);
    *(ushort4*)&Bs[(size_t)(z * 256 + c0 + r) * 512 + k0 + c4] = o;
}

// ---------- fc_w fp32 [512][65536] -> bf16 transposed [65536][512] ----------
__global__ __launch_bounds__(256) void cvt_transpose(const float* __restrict__ W,
                                                     u16* __restrict__ Bt) {
    __shared__ float t[32][33];
    int n0 = blockIdx.x * 32, k0 = blockIdx.y * 32;
    int r  = threadIdx.x >> 3, c4 = (threadIdx.x & 7) * 4;
    float4 v = *(const float4*)&W[(size_t)(k0 + r) * 65536 + n0 + c4];
    t[r][c4] = v.x; t[r][c4 + 1] = v.y; t[r][c4 + 2] = v.z; t[r][c4 + 3] = v.w;
    __syncthreads();
    ushort4 o;
    o.x = f2b(t[c4 + 0][r]); o.y = f2b(t[c4 + 1][r]);
    o.z = f2b(t[c4 + 2][r]); o.w = f2b(t[c4 + 3][r]);
    *(ushort4*)&Bt[(size_t)(n0 + r) * 512 + k0 + c4] = o;
}

// ---------- slots = mu + exp(0.5*sig)*eps,  layout [t][m][d] ----------
__global__ __launch_bounds__(256) void slots_kernel(const float* __restrict__ P,
                                                    const float* __restrict__ eps,
                                                    float* __restrict__ slots) {
    int t = blockIdx.x, d = threadIdx.x;
    float mu = P[(size_t)t * 1024 + d];
    float sg = expf(0.5f * P[(size_t)t * 1024 + 256 + d]);
    int b = t >> 6, n = t & 63;
    #pragma unroll
    for (int m = 0; m < 2; m++) {
        float e = eps[(size_t)(((b * 2 + m) * 64) + n) * 256 + d];
        slots[(size_t)t * 512 + m * 256 + d] = mu + sg * e;
    }
}

// ---------- small MFMA GEMM (fp32 out): P = Eb * Bsm^T ----------
__global__ __launch_bounds__(256, 2) void gemm_small(const u16* __restrict__ A,
                                                     const u16* __restrict__ B,
                                                     float* __restrict__ C,
                                                     int N, int K,
                                                     int nbx_l2, int bypx_l2) {
    __shared__ __align__(16) u16 As[128 * 64];
    __shared__ __align__(16) u16 Bs[128 * 64];
    int tid = threadIdx.x;
    int wave = tid >> 6, lane = tid & 63;

    int id = blockIdx.x;
    int xcd = id & 7, sq = id >> 3;
    int by = (xcd << bypx_l2) + (sq >> nbx_l2);
    int bx = sq & ((1 << nbx_l2) - 1);
    int m0 = bx * 128, n0 = by * 128;
    int wm = wave >> 1, wn = wave & 1;

    floatx4 acc[4][4];
    #pragma unroll
    for (int r = 0; r < 4; r++)
        #pragma unroll
        for (int c = 0; c < 4; c++)
            #pragma unroll
            for (int q = 0; q < 4; q++) acc[r][c][q] = 0.f;

    int lrsub = lane >> 3, kcl = lane & 7;
    const u16* gA[4]; const u16* gB[4]; u16* lA[4]; u16* lB[4];
    #pragma unroll
    for (int j = 0; j < 4; j++) {
        int r0 = (wave * 4 + j) * 8;
        int row = r0 + lrsub;
        int kof = (kcl ^ (row & 7)) * 8;
        gA[j] = A + (size_t)(m0 + row) * K + kof;
        gB[j] = B + (size_t)(n0 + row) * K + kof;
        lA[j] = As + r0 * 64;
        lB[j] = Bs + r0 * 64;
    }

    int arb = wm * 64 + (lane & 15);
    int brb = wn * 64 + (lane & 15);
    int axr = arb & 7, bxr = brb & 7;
    int cl0 = lane >> 4;

    for (int k0 = 0; k0 < K; k0 += 64) {
        #pragma unroll
        for (int j = 0; j < 4; j++) glds16(gA[j] + k0, lA[j]);
        #pragma unroll
        for (int j = 0; j < 4; j++) glds16(gB[j] + k0, lB[j]);
        __syncthreads();
        #pragma unroll
        for (int s = 0; s < 2; s++) {
            shortx8 af[4], bf[4];
            int ac = ((s * 4 + cl0) ^ axr) * 8;
            int bc = ((s * 4 + cl0) ^ bxr) * 8;
            #pragma unroll
            for (int r = 0; r < 4; r++) af[r] = *(const shortx8*)(As + (arb + r * 16) * 64 + ac);
            #pragma unroll
            for (int c = 0; c < 4; c++) bf[c] = *(const shortx8*)(Bs + (brb + c * 16) * 64 + bc);
            #pragma unroll
            for (int r = 0; r < 4; r++)
                #pragma unroll
                for (int c = 0; c < 4; c++)
                    acc[r][c] = __builtin_amdgcn_mfma_f32_16x16x32_bf16(af[r], bf[c], acc[r][c], 0, 0, 0);
        }
        __syncthreads();
    }

    int crow0 = m0 + wm * 64 + (lane >> 4) * 4;
    int ccol  = n0 + wn * 64 + (lane & 15);
    #pragma unroll
    for (int r = 0; r < 4; r++)
        #pragma unroll
        for (int c = 0; c < 4; c++)
            #pragma unroll
            for (int q = 0; q < 4; q++)
                C[(size_t)(crow0 + r * 16 + q) * N + ccol + c * 16] = acc[r][c][q];
}

// ---------- y init: Y[t][m][h] = bias[t][h] (pre-accumulation) ----------
__global__ __launch_bounds__(256) void init_y(const float* __restrict__ P,
                                              float* __restrict__ Y, int bias_col) {
    int t = blockIdx.x, h = threadIdx.x;
    float b = P[(size_t)t * 1024 + bias_col + h];
    Y[((size_t)t * 2 + 0) * 256 + h] = b;
    Y[((size_t)t * 2 + 1) * 256 + h] = b;
}

// ---------- fused mixture-GEMM + apply ----------
// Block = (token-tile 128, h-tile 64, g-group 16).  For each g: 128x64x512
// MFMA tile of W = E @ fcw^T; y-regs += s[t][m][g] * W-tile; epilogue = 64
// fp32 atomicAdds/thread into Y (bias-pre-inited).  W never hits memory.
__global__ __launch_bounds__(256, 2) void fused_mlp(const u16* __restrict__ Eb,
                                                    const u16* __restrict__ Bt,
                                                    const float* __restrict__ S,
                                                    float* __restrict__ Y,
                                                    int relu_s) {
    __shared__ __align__(16) u16 As[128 * 64];   // 16 KB
    __shared__ __align__(16) u16 Bs[64 * 64];    // 8 KB
    __shared__ float sl[16 * 2 * 128];           // [g][m][t] 16 KB
    int tid = threadIdx.x;
    int wave = tid >> 6, lane = tid & 63;

    // decode with XCD-affinity on (hh,gg): same-B blocks share an XCD and are
    // consecutive in dispatch order (L2 temporal locality).
    int id = blockIdx.x;
    int xcd = id & 7;
    int rest = id >> 3;
    int tt = rest & 15;
    int chi = rest >> 4;             // 0..7
    int combo = chi * 8 + xcd;       // 0..63
    int hh = combo >> 4;             // 0..3
    int gg = combo & 15;             // 0..15
    int m0 = tt * 128;
    int h0 = hh * 64;
    int g0 = gg * 16;

    // stage s-slice (coalesced 64B runs in g)
    {
        int g = tid & 15, m = (tid >> 4) & 1, tb = tid >> 5;
        for (int p = 0; p < 16; p++) {
            int t = tb + p * 8;
            float v = S[((size_t)(m0 + t) * 2 + m) * 256 + g0 + g];
            if (relu_s) v = fmaxf(v, 0.f);
            sl[(g * 2 + m) * 128 + t] = v;
        }
    }

    int wm = wave >> 1, wn = wave & 1;
    int lrsub = lane >> 3, kcl = lane & 7;

    const u16* gA[4]; u16* lA[4];
    #pragma unroll
    for (int j = 0; j < 4; j++) {
        int r0 = (wave * 4 + j) * 8;
        int row = r0 + lrsub;
        int kof = (kcl ^ (row & 7)) * 8;
        gA[j] = Eb + (size_t)(m0 + row) * 512 + kof;
        lA[j] = As + r0 * 64;
    }
    const u16* gB[2]; u16* lB[2];
    #pragma unroll
    for (int j = 0; j < 2; j++) {
        int r0 = (wave * 2 + j) * 8;
        int row = r0 + lrsub;
        int kof = (kcl ^ (row & 7)) * 8;
        gB[j] = Bt + ((size_t)g0 * 256 + h0 + row) * 512 + kof;
        lB[j] = Bs + r0 * 64;
    }

    int arb = wm * 64 + (lane & 15);
    int brb = wn * 32 + (lane & 15);
    int axr = arb & 7, bxr = brb & 7;
    int cl0 = lane >> 4;

    floatx4 yreg[2][4][2];
    #pragma unroll
    for (int m = 0; m < 2; m++)
        #pragma unroll
        for (int r = 0; r < 4; r++)
            #pragma unroll
            for (int c = 0; c < 2; c++)
                #pragma unroll
                for (int q = 0; q < 4; q++) yreg[m][r][c][q] = 0.f;

    for (int gi = 0; gi < 16; gi++) {
        size_t gof = (size_t)gi * 256 * 512;
        floatx4 acc[4][2];
        #pragma unroll
        for (int r = 0; r < 4; r++)
            #pragma unroll
            for (int c = 0; c < 2; c++)
                #pragma unroll
                for (int q = 0; q < 4; q++) acc[r][c][q] = 0.f;

        for (int k0 = 0; k0 < 512; k0 += 64) {
            #pragma unroll
            for (int j = 0; j < 4; j++) glds16(gA[j] + k0, lA[j]);
            #pragma unroll
            for (int j = 0; j < 2; j++) glds16(gB[j] + gof + k0, lB[j]);
            __syncthreads();
            #pragma unroll
            for (int s = 0; s < 2; s++) {
                shortx8 af[4], bf[2];
                int ac = ((s * 4 + cl0) ^ axr) * 8;
                int bc = ((s * 4 + cl0) ^ bxr) * 8;
                #pragma unroll
                for (int r = 0; r < 4; r++) af[r] = *(const shortx8*)(As + (arb + r * 16) * 64 + ac);
                #pragma unroll
                for (int c = 0; c < 2; c++) bf[c] = *(const shortx8*)(Bs + (brb + c * 16) * 64 + bc);
                #pragma unroll
                for (int r = 0; r < 4; r++)
                    #pragma unroll
                    for (int c = 0; c < 2; c++)
                        acc[r][c] = __builtin_amdgcn_mfma_f32_16x16x32_bf16(af[r], bf[c], acc[r][c], 0, 0, 0);
            }
            __syncthreads();
        }

        // y += s * W-tile  (sl reads are wave-broadcast: lanes 0..15 same addr)
        #pragma unroll
        for (int m = 0; m < 2; m++) {
            float4 sq[4];
            #pragma unroll
            for (int r = 0; r < 4; r++)
                sq[r] = *(const float4*)&sl[(gi * 2 + m) * 128 + wm * 64 + cl0 * 4 + r * 16];
            #pragma unroll
            for (int r = 0; r < 4; r++)
                #pragma unroll
                for (int c = 0; c < 2; c++)
                    #pragma unroll
                    for (int q = 0; q < 4; q++)
                        yreg[m][r][c][q] += ((const float*)&sq[r])[q] * acc[r][c][q];
        }
    }

    // atomic epilogue into Y[t][m][h]
    int l16 = lane & 15;
    #pragma unroll
    for (int m = 0; m < 2; m++)
        #pragma unroll
        for (int r = 0; r < 4; r++)
            #pragma unroll
            for (int c = 0; c < 2; c++)
                #pragma unroll
                for (int q = 0; q < 4; q++) {
                    int t = m0 + wm * 64 + cl0 * 4 + r * 16 + q;
                    int h = h0 + wn * 32 + c * 16 + l16;
                    atomicAdd(&Y[((size_t)t * 2 + m) * 256 + h], yreg[m][r][c][q]);
                }
}

// ---------- final: out[(b*2+m)*64+n][h] = relu(Y2[t][m][h]) ----------
__global__ __launch_bounds__(256) void final_out(const float* __restrict__ Y,
                                                 float* __restrict__ out) {
    int t = blockIdx.x, h = threadIdx.x;
    int b = t >> 6, n = t & 63;
    #pragma unroll
    for (int m = 0; m < 2; m++)
        out[((size_t)((b * 2 + m) * 64) + n) * 256 + h] =
            fmaxf(Y[((size_t)t * 2 + m) * 256 + h], 0.f);
}

// ---------- host ----------
extern "C" void kernel_launch(void* const* d_in, const int* in_sizes, int n_in,
                              void* d_out, int out_size, void* d_ws, size_t ws_size,
                              hipStream_t stream) {
    const float* enc = (const float*)d_in[0];
    const float* mu  = (const float*)d_in[1];
    const float* sg  = (const float*)d_in[2];
    const float* f1w = (const float*)d_in[3];
    const float* f1b = (const float*)d_in[4];
    const float* f2w = (const float*)d_in[5];
    const float* f2b = (const float*)d_in[6];
    const float* eps = (const float*)d_in[7];
    float* out = (float*)d_out;

    size_t off = 0;
    auto alloc = [&](size_t b) -> char* {
        char* p = (char*)d_ws + off; off += (b + 255) & ~(size_t)255; return p;
    };
    u16*   Eb    = (u16*)  alloc((size_t)2048 * 512 * 2);
    float* P     = (float*)alloc((size_t)2048 * 1024 * 4);
    float* slots = (float*)alloc((size_t)2048 * 512 * 4);
    float* Y1    = (float*)alloc((size_t)2048 * 512 * 4);
    float* Y2    = (float*)alloc((size_t)2048 * 512 * 4);
    u16*   Bsm   = (u16*)  alloc((size_t)1024 * 512 * 2);
    u16*   Bt    = (u16*)  alloc((size_t)65536 * 512 * 2);

    cvt_bf16_kernel<<<1024, 256, 0, stream>>>(enc, Eb, 2048 * 512);
    build_bsmall_t<<<dim3(16, 8, 4), 256, 0, stream>>>(mu, sg, f1b, f2b, Bsm);
    gemm_small<<<128, 256, 0, stream>>>(Eb, Bsm, P, 1024, 512, 4, 0);
    slots_kernel<<<2048, 256, 0, stream>>>(P, eps, slots);

    // layer 1
    cvt_transpose<<<dim3(2048, 16), 256, 0, stream>>>(f1w, Bt);
    init_y<<<2048, 256, 0, stream>>>(P, Y1, 512);
    fused_mlp<<<1024, 256, 0, stream>>>(Eb, Bt, slots, Y1, 0);

    // layer 2 (relu folded into s-loader)
    cvt_transpose<<<dim3(2048, 16), 256, 0, stream>>>(f2w, Bt);
    init_y<<<2048, 256, 0, stream>>>(P, Y2, 768);
    fused_mlp<<<1024, 256, 0, stream>>>(Eb, Bt, Y1, Y2, 1);

    final_out<<<2048, 256, 0, stream>>>(Y2, out);
}